// Round 13
// baseline (416.795 us; speedup 1.0000x reference)
//
#include <hip/hip_runtime.h>

// LIF scan over T=16: mem_t = beta*mem + x_t - spk_{t-1}; spk_t = (mem_t - 1) > 0.
// Neurons independent -> 1 thread owns 16 neurons (4 dense f4 chunks) across all T.
//
// R16 = R12/R15 (confirmed best: 225.2 us headline, dispatches < 79.6 us) plus
// ONE new variable: chip-wide phase alignment. R12's win (barrier-separated
// unidirectional R/W bursts) is per-block; blocks drift across passes, so the
// DRAM/fabric still sees up to 32 strided regions with continuous R/W mixing
// chip-wide, vs 2 regions for a dense copy (6.29 TB/s) -- we sit at 3.5 TB/s
// logical with NO per-CU resource near a limit. This round: a grid-wide
// TIMING-ONLY barrier at each pass boundary (7 total) so all 512 blocks do
// pass-p reads together, then writes together -> <=4 active 8-MB regions
// chip-wide at any instant.
// Safety: correctness NEVER depends on the barrier (each block writes only its
// own output); the spin is bounded (worst case = no alignment, never hangs);
// all 512 blocks are co-resident (2 blocks/CU); counter is memset-zeroed per
// launch (stream-ordered, graph-capture-safe -- harness itself enqueues
// memsets). Null => both local and global ordering levers exhausted =>
// declare roofline on R15 next round. Regression => revert R15.

constexpr int   T      = 16;
constexpr float BETA   = 0.9f;
constexpr float THRESH = 1.0f;
constexpr unsigned int NBLOCKS = 512;

typedef float f4 __attribute__((ext_vector_type(4)));

__global__ __launch_bounds__(256, 4) void lif_kernel(const float* __restrict__ x,
                                                     float* __restrict__ out,
                                                     int n_per_t,
                                                     unsigned int* gbar) {
    // No FMA contraction: must match numpy's two-rounding fp32 exactly, else
    // ~1-ulp drift flips spikes at the threshold (absmax = 1.0 cascades).
#pragma clang fp contract(off)
    // Block owns 4096 consecutive floats per plane as 4 chunks of 1024;
    // thread owns 4 f4 slots at c*1024 + tid*4. Clamp (not early-return) so
    // every thread reaches the barriers; with n_per_t = 2,097,152 and 512
    // blocks the clamp never engages.
    int base = blockIdx.x * 4096 + threadIdx.x * 4;
    if (base + 3072 + 4 > n_per_t) base = 0;  // degenerate-safe duplicate work

    // Persistent recurrence state, registers only.
    f4 m[4] = {(f4)(0.f), (f4)(0.f), (f4)(0.f), (f4)(0.f)};
    f4 s[4] = {(f4)(0.f), (f4)(0.f), (f4)(0.f), (f4)(0.f)};

    for (int pass = 0; pass < 8; ++pass) {
        const int t0 = pass * 2;

        // READ region: 8 coalesced f4 loads (2 planes x 4 chunks), one
        // unidirectional burst; 16 KB dense run per plane at block scope.
        f4 r[2][4];
#pragma unroll
        for (int p = 0; p < 2; ++p) {
            const size_t off = (size_t)(t0 + p) * (size_t)n_per_t + (size_t)base;
#pragma unroll
            for (int c = 0; c < 4; ++c)
                r[p][c] = *reinterpret_cast<const f4*>(x + off + c * 1024);
        }

        // Compute: 2 recurrence steps; results overwrite r.
#pragma unroll
        for (int p = 0; p < 2; ++p) {
#pragma unroll
            for (int c = 0; c < 4; ++c) {
#pragma unroll
                for (int j = 0; j < 4; ++j) {
                    m[c][j] = BETA * m[c][j] + r[p][c][j] - s[c][j] * THRESH;
                    s[c][j] = (m[c][j] - THRESH) > 0.f ? 1.f : 0.f;
                }
                r[p][c] = s[c];
            }
        }

        // Region boundary: stores may not hoist above, loads may not sink below.
        __syncthreads();

        // WRITE region: 8-store unidirectional burst (plain cacheable stores).
#pragma unroll
        for (int p = 0; p < 2; ++p) {
            const size_t off = (size_t)(t0 + p) * (size_t)n_per_t + (size_t)base;
#pragma unroll
            for (int c = 0; c < 4; ++c)
                *reinterpret_cast<f4*>(out + off + c * 1024) = r[p][c];
        }

        // Region boundary: next pass's loads stay after this store burst.
        __syncthreads();

        // Grid-wide TIMING-ONLY barrier (7 interior boundaries): align all 512
        // blocks at pass granularity so chip-wide reads/writes stay confined
        // to the same 2+2 planes. Bounded spin -- worst case it releases early
        // and we merely lose alignment; output correctness is unaffected.
        if (gbar != nullptr && pass < 7) {
            if (threadIdx.x == 0) {
                const unsigned int old    = atomicAdd(gbar, 1u);   // device scope
                const unsigned int target = ((old / NBLOCKS) + 1u) * NBLOCKS;
                for (int it = 0; it < (1 << 14); ++it) {           // ~1.6 ms cap
                    const unsigned int v = __hip_atomic_load(
                        gbar, __ATOMIC_RELAXED, __HIP_MEMORY_SCOPE_AGENT);
                    if (v >= target) break;
                    __builtin_amdgcn_s_sleep(4);                   // ~256 cycles
                }
            }
            __syncthreads();
        }
    }
}

extern "C" void kernel_launch(void* const* d_in, const int* in_sizes, int n_in,
                              void* d_out, int out_size, void* d_ws, size_t ws_size,
                              hipStream_t stream) {
    const float* x   = (const float*)d_in[0];
    float*       out = (float*)d_out;

    const int total   = in_sizes[0];      // 33,554,432
    const int n_per_t = total / T;        // 2,097,152 (divisible by 4096)
    const int blocks  = n_per_t / 4096;   // 512 blocks, 256 threads, 16 floats/thread

    unsigned int* gbar = nullptr;
    if (d_ws != nullptr && ws_size >= sizeof(unsigned int)) {
        gbar = (unsigned int*)d_ws;
        // Stream-ordered zero of the barrier counter: graph-capture-safe
        // (stream-ordered memset, same class the harness's reset() enqueues).
        hipMemsetAsync(gbar, 0, sizeof(unsigned int), stream);
    }

    lif_kernel<<<dim3(blocks), dim3(256), 0, stream>>>(x, out, n_per_t, gbar);
}